// Round 2
// baseline (9205.022 us; speedup 1.0000x reference)
//
#include <hip/hip_runtime.h>
#include <stdint.h>
#include <stddef.h>

// ---------------- problem constants ----------------
#define BATCH 64
#define TT    512
#define DIM   256
#define HID   256
#define MROWS (BATCH*TT)     // 32768

typedef unsigned short u16;
typedef __attribute__((ext_vector_type(8))) short  short8;   // 8 x bf16 bits (4 VGPRs) - MFMA A/B frag
typedef __attribute__((ext_vector_type(4))) float  f32x4;    // MFMA C/D frag
typedef __attribute__((ext_vector_type(4))) unsigned short u16x4;

__device__ __forceinline__ u16 bf16_hi(float f) {
    union { float f; unsigned u; } v; v.f = f;
    unsigned r = v.u + 0x7fffu + ((v.u >> 16) & 1u);   // RNE
    return (u16)(r >> 16);
}
__device__ __forceinline__ float bf16f(u16 b) {
    union { unsigned u; float f; } v; v.u = ((unsigned)b) << 16;
    return v.f;
}
__device__ __forceinline__ float fsigmoid(float x) { return 1.f / (1.f + __expf(-x)); }
__device__ __forceinline__ float ftanh(float x) {
    x = fminf(15.f, fmaxf(-15.f, x));                  // avoid inf/inf
    float e = __expf(2.f * x);
    return (e - 1.f) / (e + 1.f);
}

// ---------------- prep: quantize weights to bf16 hi/lo, bias sums, zero flags ----------------
// elems: Wih0 f+b 524288 | Whh0 524288 | Wih1 f+b 1048576 | Whh1 524288 = 2,621,440
__global__ __launch_bounds__(256) void k_prep(
    const float* __restrict__ Wih0f, const float* __restrict__ Whh0f, const float* __restrict__ bih0f, const float* __restrict__ bhh0f,
    const float* __restrict__ Wih0b, const float* __restrict__ Whh0b, const float* __restrict__ bih0b, const float* __restrict__ bhh0b,
    const float* __restrict__ Wih1f, const float* __restrict__ Whh1f, const float* __restrict__ bih1f, const float* __restrict__ bhh1f,
    const float* __restrict__ Wih1b, const float* __restrict__ Whh1b, const float* __restrict__ bih1b, const float* __restrict__ bhh1b,
    u16* __restrict__ WihQ0hi, u16* __restrict__ WihQ0lo,
    u16* __restrict__ WhhQ0hi, u16* __restrict__ WhhQ0lo,
    u16* __restrict__ WihQ1hi, u16* __restrict__ WihQ1lo,
    u16* __restrict__ WhhQ1hi, u16* __restrict__ WhhQ1lo,
    float* __restrict__ bsum, int* __restrict__ flags)
{
    const int i = blockIdx.x * 256 + threadIdx.x;
    if (i < 2621440) {
        const float* src; u16* dhi; u16* dlo; int off;
        if      (i <  262144) { src = Wih0f; dhi = WihQ0hi;          dlo = WihQ0lo;          off = i; }
        else if (i <  524288) { src = Wih0b; dhi = WihQ0hi + 262144; dlo = WihQ0lo + 262144; off = i -  262144; }
        else if (i <  786432) { src = Whh0f; dhi = WhhQ0hi;          dlo = WhhQ0lo;          off = i -  524288; }
        else if (i < 1048576) { src = Whh0b; dhi = WhhQ0hi + 262144; dlo = WhhQ0lo + 262144; off = i -  786432; }
        else if (i < 1572864) { src = Wih1f; dhi = WihQ1hi;          dlo = WihQ1lo;          off = i - 1048576; }
        else if (i < 2097152) { src = Wih1b; dhi = WihQ1hi + 524288; dlo = WihQ1lo + 524288; off = i - 1572864; }
        else if (i < 2359296) { src = Whh1f; dhi = WhhQ1hi;          dlo = WhhQ1lo;          off = i - 2097152; }
        else                  { src = Whh1b; dhi = WhhQ1hi + 262144; dlo = WhhQ1lo + 262144; off = i - 2359296; }
        const float v = src[off];
        const u16 h = bf16_hi(v);
        dhi[off] = h;
        dlo[off] = bf16_hi(v - bf16f(h));
    } else if (i < 2621440 + 4096) {
        const int j = i - 2621440;
        const float* bihs[4] = { bih0f, bih0b, bih1f, bih1b };
        const float* bhhs[4] = { bhh0f, bhh0b, bhh1f, bhh1b };
        const int ld = j >> 10, k = j & 1023;
        bsum[j] = bihs[ld][k] + bhhs[ld][k];
    } else if (i < 2621440 + 4096 + 256) {
        flags[i - (2621440 + 4096)] = 0;
    }
}

// ---------------- embedding gather -> A0 (bf16 hi only) ----------------
__global__ __launch_bounds__(256) void k_gather(
    const int* __restrict__ x, const float* __restrict__ embed, u16* __restrict__ A0)
{
    const int row = blockIdx.x * 4 + (threadIdx.x >> 6);
    const int col = (threadIdx.x & 63) * 4;
    const int xi = x[row];
    const f32x4 v = *(const f32x4*)(embed + (size_t)xi * DIM + col);
    u16x4 h;
    #pragma unroll
    for (int i = 0; i < 4; i++) h[i] = bf16_hi(v[i]);
    *(u16x4*)(A0 + (size_t)row * DIM + col) = h;
}

// ---------------- persistent bidirectional LSTM layer (input projection folded in) ----------------
// grid = 128 blocks: bid = s*8 + d*4 + c   (s = 16-unit slice 0..15, d = dir, c = batch-chunk of 16)
// Wave w == gate w (i,f,g,o): 16 gate-rows, all weights (Whh hi/lo 3-term, Wih hi/lo x 2-term) in registers.
// Per step: stage x-tile + h-tile into swizzled LDS; 40/56 MFMAs per wave; gate exchange via LDS;
// cell update; publish h slice; flag release (agent scope). 16 blocks per (d,c) exchange group.
template<int KIN, bool WRITE_H, bool POOL>
__global__ __launch_bounds__(256, 1) void k_lstm(
    const u16* __restrict__ Xin,                   // layer0: A0 [32768][256]; layer1: H0 [32768][512]
    const u16* __restrict__ WhhHi, const u16* __restrict__ WhhLo,   // [2][1024][256]
    const u16* __restrict__ WihHi, const u16* __restrict__ WihLo,   // [2][1024][KIN]
    const float* __restrict__ bsum,                // [2][1024] for this layer
    const int* __restrict__ slen,
    u16* __restrict__ H0,                          // layer0 out (hi) [32768][512] or null
    float* __restrict__ outp,                      // [64][512] pooled out or null
    u16* __restrict__ hxhi, u16* __restrict__ hxlo, // [2 parity][2 dir][64][256]
    int* __restrict__ flags)                       // [8 groups][16 slices]
{
    constexpr int KV = KIN / 32;        // MFMA k-blocks for input proj
    constexpr int CR = KIN / 8;         // 16B chunks per x row
    constexpr int NST = (16 * CR) / 256;

    const int bid = blockIdx.x;
    const int s = bid >> 3;
    const int d = (bid >> 2) & 1;
    const int c = bid & 3;
    const int tid = threadIdx.x;
    const int l = tid & 63, w = tid >> 6;

    __shared__ u16 xs[16 * KIN];        // swizzled x-tile (bf16 hi)
    __shared__ u16 hs_hi[16 * 256];
    __shared__ u16 hs_lo[16 * 256];
    __shared__ float g_lds[64 * 16];    // [gate*16+unit][batch]
    __shared__ u16 ho_hi[16 * 16];      // [batch][unit]
    __shared__ u16 ho_lo[16 * 16];
    __shared__ int lens_sh[16];
    __shared__ int maxlen_sh;

    if (tid < 16) lens_sh[tid] = slen[c * 16 + tid];
    __syncthreads();
    if (tid == 0) {
        int m = 0;
        #pragma unroll
        for (int i = 0; i < 16; i++) m = max(m, lens_sh[i]);
        maxlen_sh = m;
    }
    __syncthreads();
    const int maxlen = maxlen_sh;

    // ---- persistent register-resident weight fragments (wave w = gate w) ----
    const int rbase = d * 1024 + w * 256 + s * 16;
    short8 wfh[8], wfl[8];
    #pragma unroll
    for (int kv = 0; kv < 8; kv++) {
        const size_t off = (size_t)(rbase + (l & 15)) * 256 + kv * 32 + ((l >> 4) << 3);
        wfh[kv] = *(const short8*)(WhhHi + off);
        wfl[kv] = *(const short8*)(WhhLo + off);
    }
    short8 uih[KV], uil[KV];
    #pragma unroll
    for (int kv = 0; kv < KV; kv++) {
        const size_t off = (size_t)(rbase + (l & 15)) * KIN + kv * 32 + ((l >> 4) << 3);
        uih[kv] = *(const short8*)(WihHi + off);
        uil[kv] = *(const short8*)(WihLo + off);
    }
    // per-thread bias (cell-update mapping: u = tid>>4, bi = tid&15)
    float bias_g[4];
    {
        const int u = tid >> 4;
        #pragma unroll
        for (int g = 0; g < 4; g++) bias_g[g] = bsum[d * 1024 + g * 256 + s * 16 + u];
    }

    int* flg = flags + (d * 4 + c) * 16;
    float creg = 0.f, mx = -1e30f;
    const int bi_m = l & 15;
    const int swz = bi_m & 7;
    const int klane = l >> 4;

    for (int t = 0; t < maxlen; ++t) {
        // ---- stage x-tile (independent of h; overlaps flag wait) ----
        #pragma unroll
        for (int p = 0; p < NST; p++) {
            const int idx = p * 256 + tid;
            const int bi = idx / CR;
            const int ch = idx % CR;
            const int len_b = lens_sh[bi];
            const int pos = (d == 0) ? t : ((t < len_b) ? (len_b - 1 - t) : t);
            const short8 v = *(const short8*)(Xin + ((size_t)(c * 16 + bi) * TT + pos) * KIN + ch * 8);
            *(short8*)(xs + bi * KIN + (ch ^ (bi & 7)) * 8) = v;
        }

        // ---- obtain h(t) ----
        if (t == 0) {
            const short8 z = {0,0,0,0,0,0,0,0};
            for (int i = tid; i < 512; i += 256) {
                ((short8*)hs_hi)[i] = z;
                ((short8*)hs_lo)[i] = z;
            }
        } else {
            if (tid < 16) {
                int spins = 0;
                while (__hip_atomic_load(&flg[tid], __ATOMIC_RELAXED, __HIP_MEMORY_SCOPE_AGENT) < t) {
                    __builtin_amdgcn_s_sleep(4);
                    if (++spins > (1 << 15)) break;   // safety valve: degrade, don't hang
                }
            }
            __syncthreads();
            __builtin_amdgcn_fence(__ATOMIC_ACQUIRE, "agent");   // invalidate stale cache before hx reads
            const u16* srchi = hxhi + ((size_t)((t & 1) * 2 + d) * 64 + c * 16) * 256;
            const u16* srclo = hxlo + ((size_t)((t & 1) * 2 + d) * 64 + c * 16) * 256;
            #pragma unroll
            for (int p = 0; p < 2; p++) {
                const int idx = p * 256 + tid;
                const int bi = idx >> 5;
                const int ch = idx & 31;
                const int sc = ch ^ (bi & 7);
                *(short8*)(hs_hi + bi * 256 + sc * 8) = *(const short8*)(srchi + bi * 256 + ch * 8);
                *(short8*)(hs_lo + bi * 256 + sc * 8) = *(const short8*)(srclo + bi * 256 + ch * 8);
            }
        }
        __syncthreads();   // S1: xs & hs ready

        // ---- gates = Whh.h (3-term) + Wih.x (2-term) ----
        f32x4 acc = {0.f, 0.f, 0.f, 0.f};
        #pragma unroll
        for (int kv = 0; kv < 8; kv++) {
            const int kc = kv * 4 + klane;
            const short8 bh = *(const short8*)(hs_hi + bi_m * 256 + (kc ^ swz) * 8);
            const short8 bl = *(const short8*)(hs_lo + bi_m * 256 + (kc ^ swz) * 8);
            acc = __builtin_amdgcn_mfma_f32_16x16x32_bf16(wfh[kv], bh, acc, 0, 0, 0);
            acc = __builtin_amdgcn_mfma_f32_16x16x32_bf16(wfl[kv], bh, acc, 0, 0, 0);
            acc = __builtin_amdgcn_mfma_f32_16x16x32_bf16(wfh[kv], bl, acc, 0, 0, 0);
        }
        #pragma unroll
        for (int kv = 0; kv < KV; kv++) {
            const int kc = kv * 4 + klane;
            const short8 bx = *(const short8*)(xs + bi_m * KIN + (kc ^ swz) * 8);
            acc = __builtin_amdgcn_mfma_f32_16x16x32_bf16(uih[kv], bx, acc, 0, 0, 0);
            acc = __builtin_amdgcn_mfma_f32_16x16x32_bf16(uil[kv], bx, acc, 0, 0, 0);
        }
        {
            const int r0 = w * 16 + klane * 4;
            #pragma unroll
            for (int r = 0; r < 4; r++) g_lds[(r0 + r) * 16 + bi_m] = acc[r];
        }
        __syncthreads();   // S2

        // ---- cell update: thread -> (unit u, batch bi) ----
        {
            const int u = tid >> 4, bi = tid & 15;
            const float gi = g_lds[( 0 + u) * 16 + bi] + bias_g[0];
            const float gf = g_lds[(16 + u) * 16 + bi] + bias_g[1];
            const float gg = g_lds[(32 + u) * 16 + bi] + bias_g[2];
            const float go = g_lds[(48 + u) * 16 + bi] + bias_g[3];
            const float cc = fsigmoid(gf) * creg + fsigmoid(gi) * ftanh(gg);
            creg = cc;
            const float h = fsigmoid(go) * ftanh(cc);
            if (POOL && t < lens_sh[bi]) mx = fmaxf(mx, h);
            const u16 hh = bf16_hi(h);
            ho_hi[bi * 16 + u] = hh;
            ho_lo[bi * 16 + u] = bf16_hi(h - bf16f(hh));
        }
        __syncthreads();   // S3

        // ---- publish h(t+1): wave0 -> hx hi, wave1 -> hx lo, wave2 -> H0 (layer0) ----
        if (l < 32) {
            const int bi = l >> 1, half = l & 1;
            const size_t hxoff = ((size_t)(((t + 1) & 1) * 2 + d) * 64 + c * 16 + bi) * 256 + s * 16 + half * 8;
            if (w == 0) {
                *(short8*)(hxhi + hxoff) = *(const short8*)(ho_hi + bi * 16 + half * 8);
            } else if (w == 1) {
                *(short8*)(hxlo + hxoff) = *(const short8*)(ho_lo + bi * 16 + half * 8);
            } else if (WRITE_H && w == 2) {
                const int len_b = lens_sh[bi];
                const int pos = (d == 0) ? t : ((t < len_b) ? (len_b - 1 - t) : t);
                *(short8*)(H0 + ((size_t)(c * 16 + bi) * TT + pos) * 512 + d * 256 + s * 16 + half * 8)
                    = *(const short8*)(ho_hi + bi * 16 + half * 8);
            }
        }
        __syncthreads();   // S4: all waves' stores drained (vmcnt 0) before release
        if (tid == 0)
            __hip_atomic_store(&flg[s], t + 1, __ATOMIC_RELEASE, __HIP_MEMORY_SCOPE_AGENT);
    }

    if (POOL) {
        const int u = tid >> 4, bi = tid & 15;
        outp[(size_t)(c * 16 + bi) * 512 + d * 256 + s * 16 + u] = mx;
    }
}

// ---------------- host launch ----------------
extern "C" void kernel_launch(void* const* d_in, const int* in_sizes, int n_in,
                              void* d_out, int out_size, void* d_ws, size_t ws_size,
                              hipStream_t stream)
{
    (void)in_sizes; (void)n_in; (void)out_size; (void)ws_size;
    const int*   x     = (const int*)d_in[0];
    const int*   slen  = (const int*)d_in[1];
    const float* embed = (const float*)d_in[2];
    const float* W[16];
    for (int i = 0; i < 16; i++) W[i] = (const float*)d_in[3 + i];
    // W: 0=Wih0f 1=Whh0f 2=bih0f 3=bhh0f 4=Wih0b 5=Whh0b 6=bih0b 7=bhh0b
    //    8=Wih1f 9=Whh1f 10=bih1f 11=bhh1f 12=Wih1b 13=Whh1b 14=bih1b 15=bhh1b
    float* out = (float*)d_out;

    char* p = (char*)d_ws;                                   // total ~60.7 MB
    u16* A0      = (u16*)p;   p += (size_t)MROWS * DIM * 2;  // 16.8 MB
    u16* H0      = (u16*)p;   p += (size_t)MROWS * 512 * 2;  // 33.6 MB
    u16* WihQ0hi = (u16*)p;   p += 524288 * 2;
    u16* WihQ0lo = (u16*)p;   p += 524288 * 2;
    u16* WhhQ0hi = (u16*)p;   p += 524288 * 2;
    u16* WhhQ0lo = (u16*)p;   p += 524288 * 2;
    u16* WihQ1hi = (u16*)p;   p += 1048576 * 2;
    u16* WihQ1lo = (u16*)p;   p += 1048576 * 2;
    u16* WhhQ1hi = (u16*)p;   p += 524288 * 2;
    u16* WhhQ1lo = (u16*)p;   p += 524288 * 2;
    float* bsum  = (float*)p; p += 4096 * 4;
    u16* hxhi    = (u16*)p;   p += 65536 * 2;
    u16* hxlo    = (u16*)p;   p += 65536 * 2;
    int* flags   = (int*)p;   p += 256 * 4;

    k_prep<<<10257, 256, 0, stream>>>(
        W[0], W[1], W[2], W[3], W[4], W[5], W[6], W[7],
        W[8], W[9], W[10], W[11], W[12], W[13], W[14], W[15],
        WihQ0hi, WihQ0lo, WhhQ0hi, WhhQ0lo, WihQ1hi, WihQ1lo, WhhQ1hi, WhhQ1lo,
        bsum, flags);

    k_gather<<<8192, 256, 0, stream>>>(x, embed, A0);

    k_lstm<256, true, false><<<128, 256, 0, stream>>>(
        A0, WhhQ0hi, WhhQ0lo, WihQ0hi, WihQ0lo, bsum, slen,
        H0, nullptr, hxhi, hxlo, flags);

    k_lstm<512, false, true><<<128, 256, 0, stream>>>(
        H0, WhhQ1hi, WhhQ1lo, WihQ1hi, WihQ1lo, bsum + 2048, slen,
        nullptr, out, hxhi, hxlo, flags + 128);
}

// Round 3
// 6151.641 us; speedup vs baseline: 1.4964x; 1.4964x over previous
//
#include <hip/hip_runtime.h>
#include <stdint.h>
#include <stddef.h>

// ---------------- problem constants ----------------
#define BATCH 64
#define TT    512
#define DIM   256
#define HID   256
#define MROWS (BATCH*TT)     // 32768

typedef unsigned short u16;
typedef unsigned int u32;
typedef __attribute__((ext_vector_type(8))) short  short8;   // 8 x bf16 bits (4 VGPRs) - MFMA A/B frag
typedef __attribute__((ext_vector_type(4))) float  f32x4;    // MFMA C/D frag
typedef __attribute__((ext_vector_type(4))) int    int4v;
typedef __attribute__((ext_vector_type(4))) unsigned short u16x4;

__device__ __forceinline__ u16 bf16_hi(float f) {
    union { float f; unsigned u; } v; v.f = f;
    unsigned r = v.u + 0x7fffu + ((v.u >> 16) & 1u);   // RNE
    return (u16)(r >> 16);
}
__device__ __forceinline__ float bf16f(u16 b) {
    union { unsigned u; float f; } v; v.u = ((unsigned)b) << 16;
    return v.f;
}
__device__ __forceinline__ float fsigmoid(float x) { return 1.f / (1.f + __expf(-x)); }
__device__ __forceinline__ float ftanh(float x) {
    x = fminf(15.f, fmaxf(-15.f, x));                  // avoid inf/inf
    float e = __expf(2.f * x);
    return (e - 1.f) / (e + 1.f);
}

// ---------------- prep: quantize weights to bf16 hi/lo, bias sums, init hx tag buffers ----------------
// elems: weights 2,621,440 | bsum 4096 | hx init 131072  => 2,756,608 = 10768*256
__global__ __launch_bounds__(256) void k_prep(
    const float* __restrict__ Wih0f, const float* __restrict__ Whh0f, const float* __restrict__ bih0f, const float* __restrict__ bhh0f,
    const float* __restrict__ Wih0b, const float* __restrict__ Whh0b, const float* __restrict__ bih0b, const float* __restrict__ bhh0b,
    const float* __restrict__ Wih1f, const float* __restrict__ Whh1f, const float* __restrict__ bih1f, const float* __restrict__ bhh1f,
    const float* __restrict__ Wih1b, const float* __restrict__ Whh1b, const float* __restrict__ bih1b, const float* __restrict__ bhh1b,
    u16* __restrict__ WihQ0hi, u16* __restrict__ WihQ0lo,
    u16* __restrict__ WhhQ0hi, u16* __restrict__ WhhQ0lo,
    u16* __restrict__ WihQ1hi, u16* __restrict__ WihQ1lo,
    u16* __restrict__ WhhQ1hi, u16* __restrict__ WhhQ1lo,
    float* __restrict__ bsum, u32* __restrict__ hxp)
{
    const int i = blockIdx.x * 256 + threadIdx.x;
    if (i < 2621440) {
        const float* src; u16* dhi; u16* dlo; int off;
        if      (i <  262144) { src = Wih0f; dhi = WihQ0hi;          dlo = WihQ0lo;          off = i; }
        else if (i <  524288) { src = Wih0b; dhi = WihQ0hi + 262144; dlo = WihQ0lo + 262144; off = i -  262144; }
        else if (i <  786432) { src = Whh0f; dhi = WhhQ0hi;          dlo = WhhQ0lo;          off = i -  524288; }
        else if (i < 1048576) { src = Whh0b; dhi = WhhQ0hi + 262144; dlo = WhhQ0lo + 262144; off = i -  786432; }
        else if (i < 1572864) { src = Wih1f; dhi = WihQ1hi;          dlo = WihQ1lo;          off = i - 1048576; }
        else if (i < 2097152) { src = Wih1b; dhi = WihQ1hi + 524288; dlo = WihQ1lo + 524288; off = i - 1572864; }
        else if (i < 2359296) { src = Whh1f; dhi = WhhQ1hi;          dlo = WhhQ1lo;          off = i - 2097152; }
        else                  { src = Whh1b; dhi = WhhQ1hi + 262144; dlo = WhhQ1lo + 262144; off = i - 2359296; }
        const float v = src[off];
        const u16 h = bf16_hi(v);
        dhi[off] = h;
        dlo[off] = bf16_hi(v - bf16f(h));
    } else if (i < 2621440 + 4096) {
        const int j = i - 2621440;
        const float* bihs[4] = { bih0f, bih0b, bih1f, bih1b };
        const float* bhhs[4] = { bhh0f, bhh0b, bhh1f, bhh1b };
        const int ld = j >> 10, k = j & 1023;
        bsum[j] = bihs[ld][k] + bhhs[ld][k];
    } else if (i < 2621440 + 4096 + 131072) {
        // hx: 2 layer-regions x [2 parity][2 dir][64][256] u32. Init tag must MISMATCH first
        // expected tag per parity: parity0 first used at t=2 (expect 1) -> init tag 0;
        // parity1 first used at t=1 (expect 0) -> init tag 1 (bit16).
        const int j = i - (2621440 + 4096);
        hxp[j] = ((j >> 15) & 1) ? 0x00010000u : 0u;
    }
}

// ---------------- embedding gather -> A0 (bf16 hi only) ----------------
__global__ __launch_bounds__(256) void k_gather(
    const int* __restrict__ x, const float* __restrict__ embed, u16* __restrict__ A0)
{
    const int row = blockIdx.x * 4 + (threadIdx.x >> 6);
    const int col = (threadIdx.x & 63) * 4;
    const int xi = x[row];
    const f32x4 v = *(const f32x4*)(embed + (size_t)xi * DIM + col);
    u16x4 h;
    #pragma unroll
    for (int i = 0; i < 4; i++) h[i] = bf16_hi(v[i]);
    *(u16x4*)(A0 + (size_t)row * DIM + col) = h;
}

// ---------------- persistent bidirectional LSTM layer, fence-free exchange ----------------
// grid = 128 blocks: bid = s*8 + d*4 + c (s=16-unit slice, d=dir, c=batch-chunk of 16).
// Cross-block h exchange: packed u32 (hi16|lo16) per (batch,unit), LSB of lo16 = step tag.
// Relaxed agent-scope atomics (per-access coherent) -> NO fences, NO flags, NO L2 thrash.
// Parity double-buffer + alternating tag: provably race-free (max skew 1 step).
template<int KIN, bool WRITE_H, bool POOL>
__global__ __launch_bounds__(256, 1) void k_lstm(
    const u16* __restrict__ Xin,                   // layer0: A0 [32768][256]; layer1: H0 [32768][512]
    const u16* __restrict__ WhhHi, const u16* __restrict__ WhhLo,   // [2][1024][256]
    const u16* __restrict__ WihHi, const u16* __restrict__ WihLo,   // [2][1024][KIN]
    const float* __restrict__ bsum,                // [2][1024] for this layer
    const int* __restrict__ slen,
    u16* __restrict__ H0,                          // layer0 out (hi) [32768][512] or null
    float* __restrict__ outp,                      // [64][512] pooled out or null
    u32* __restrict__ hx)                          // [2 parity][2 dir][64][256] packed
{
    constexpr int KV = KIN / 32;        // MFMA k-blocks for input proj
    constexpr int CR = KIN / 8;         // 16B chunks per x row
    constexpr int NST = (16 * CR) / 256;

    const int bid = blockIdx.x;
    const int s = bid >> 3;
    const int d = (bid >> 2) & 1;
    const int c = bid & 3;
    const int tid = threadIdx.x;
    const int l = tid & 63, w = tid >> 6;

    __shared__ u16 xs[16 * KIN];        // swizzled x-tile (bf16 hi)
    __shared__ u16 hs_hi[16 * 256];
    __shared__ u16 hs_lo[16 * 256];
    __shared__ float g_lds[64 * 16];    // [gate*16+unit][batch]
    __shared__ u16 ho_hi[16 * 16];      // [batch][unit] (layer0 output staging)
    __shared__ int lens_sh[16];
    __shared__ int maxlen_sh;

    if (tid < 16) lens_sh[tid] = slen[c * 16 + tid];
    __syncthreads();
    if (tid == 0) {
        int m = 0;
        #pragma unroll
        for (int i = 0; i < 16; i++) m = max(m, lens_sh[i]);
        maxlen_sh = m;
    }
    __syncthreads();
    const int maxlen = maxlen_sh;

    // ---- persistent register-resident weight fragments (wave w = gate w) ----
    const int rbase = d * 1024 + w * 256 + s * 16;
    short8 wfh[8], wfl[8];
    #pragma unroll
    for (int kv = 0; kv < 8; kv++) {
        const size_t off = (size_t)(rbase + (l & 15)) * 256 + kv * 32 + ((l >> 4) << 3);
        wfh[kv] = *(const short8*)(WhhHi + off);
        wfl[kv] = *(const short8*)(WhhLo + off);
    }
    short8 uih[KV], uil[KV];
    #pragma unroll
    for (int kv = 0; kv < KV; kv++) {
        const size_t off = (size_t)(rbase + (l & 15)) * KIN + kv * 32 + ((l >> 4) << 3);
        uih[kv] = *(const short8*)(WihHi + off);
        uil[kv] = *(const short8*)(WihLo + off);
    }
    float bias_g[4];
    {
        const int u = tid >> 4;
        #pragma unroll
        for (int g = 0; g < 4; g++) bias_g[g] = bsum[d * 1024 + g * 256 + s * 16 + u];
    }

    float creg = 0.f, mx = -1e30f;
    const int bi_m = l & 15;
    const int swz = bi_m & 7;
    const int klane = l >> 4;
    const int bi_ld = tid >> 4;        // consumer-load mapping: batch
    const int useg  = tid & 15;        // 16-unit segment -> one 64B line per thread

    for (int t = 0; t < maxlen; ++t) {
        // ---- stage x-tile (plain loads; L2 stays warm - no fences anywhere) ----
        #pragma unroll
        for (int p = 0; p < NST; p++) {
            const int idx = p * 256 + tid;
            const int bi = idx / CR;
            const int ch = idx % CR;
            const int len_b = lens_sh[bi];
            const int pos = (d == 0) ? t : ((t < len_b) ? (len_b - 1 - t) : t);
            const short8 v = *(const short8*)(Xin + ((size_t)(c * 16 + bi) * TT + pos) * KIN + ch * 8);
            *(short8*)(xs + bi * KIN + (ch ^ (bi & 7)) * 8) = v;
        }

        // ---- obtain h(t): self-validating coherent loads, retry until whole tile is step-t ----
        if (t == 0) {
            const short8 z = {0,0,0,0,0,0,0,0};
            for (int i = tid; i < 512; i += 256) {
                ((short8*)hs_hi)[i] = z;
                ((short8*)hs_lo)[i] = z;
            }
            __syncthreads();
        } else {
            const u32* src = hx + (((size_t)(t & 1) * 2 + d) * 64 + c * 16 + bi_ld) * 256 + useg * 16;
            const u32 expect = (u32)((t >> 1) & 1);
            u32 wbuf[16];
            for (;;) {
                u32 aw = 0xFFFFFFFFu, ow = 0u;
                #pragma unroll
                for (int k = 0; k < 16; k++) {
                    wbuf[k] = __hip_atomic_load(src + k, __ATOMIC_RELAXED, __HIP_MEMORY_SCOPE_AGENT);
                    aw &= wbuf[k]; ow |= wbuf[k];
                }
                const int ok = expect ? (int)((aw >> 16) & 1u) : (int)(((ow >> 16) & 1u) ^ 1u);
                if (__syncthreads_and(ok)) break;
                __builtin_amdgcn_s_sleep(1);
            }
            // unpack hi/lo -> swizzled LDS (2 chunks of 8 units per thread)
            #pragma unroll
            for (int hf = 0; hf < 2; hf++) {
                u32 hi4[4], lo4[4];
                #pragma unroll
                for (int q = 0; q < 4; q++) {
                    const u32 we = wbuf[hf * 8 + q * 2], wo = wbuf[hf * 8 + q * 2 + 1];
                    hi4[q] = (we & 0xFFFFu) | (wo << 16);
                    lo4[q] = (we >> 16) | (wo & 0xFFFF0000u);
                }
                const int ch = useg * 2 + hf;
                const int sc = ch ^ (bi_ld & 7);
                *(int4v*)(hs_hi + bi_ld * 256 + sc * 8) = int4v{(int)hi4[0], (int)hi4[1], (int)hi4[2], (int)hi4[3]};
                *(int4v*)(hs_lo + bi_ld * 256 + sc * 8) = int4v{(int)lo4[0], (int)lo4[1], (int)lo4[2], (int)lo4[3]};
            }
            __syncthreads();   // hs & xs ready
        }

        // ---- gates = Whh.h (3-term) + Wih.x (2-term) ----
        f32x4 acc = {0.f, 0.f, 0.f, 0.f};
        #pragma unroll
        for (int kv = 0; kv < 8; kv++) {
            const int kc = kv * 4 + klane;
            const short8 bh = *(const short8*)(hs_hi + bi_m * 256 + (kc ^ swz) * 8);
            const short8 bl = *(const short8*)(hs_lo + bi_m * 256 + (kc ^ swz) * 8);
            acc = __builtin_amdgcn_mfma_f32_16x16x32_bf16(wfh[kv], bh, acc, 0, 0, 0);
            acc = __builtin_amdgcn_mfma_f32_16x16x32_bf16(wfl[kv], bh, acc, 0, 0, 0);
            acc = __builtin_amdgcn_mfma_f32_16x16x32_bf16(wfh[kv], bl, acc, 0, 0, 0);
        }
        #pragma unroll
        for (int kv = 0; kv < KV; kv++) {
            const int kc = kv * 4 + klane;
            const short8 bx = *(const short8*)(xs + bi_m * KIN + (kc ^ swz) * 8);
            acc = __builtin_amdgcn_mfma_f32_16x16x32_bf16(uih[kv], bx, acc, 0, 0, 0);
            acc = __builtin_amdgcn_mfma_f32_16x16x32_bf16(uil[kv], bx, acc, 0, 0, 0);
        }
        {
            const int r0 = w * 16 + klane * 4;
            #pragma unroll
            for (int r = 0; r < 4; r++) g_lds[(r0 + r) * 16 + bi_m] = acc[r];
        }
        __syncthreads();   // S2: gates ready; also protects xs/g_lds overwrite next iter

        // ---- cell update + immediate publish (1 relaxed agent atomic store per thread) ----
        {
            const int u = tid >> 4, bi = tid & 15;
            const float gi = g_lds[( 0 + u) * 16 + bi] + bias_g[0];
            const float gf = g_lds[(16 + u) * 16 + bi] + bias_g[1];
            const float gg = g_lds[(32 + u) * 16 + bi] + bias_g[2];
            const float go = g_lds[(48 + u) * 16 + bi] + bias_g[3];
            const float cc = fsigmoid(gf) * creg + fsigmoid(gi) * ftanh(gg);
            creg = cc;
            const float h = fsigmoid(go) * ftanh(cc);
            const u16 hh = bf16_hi(h);
            const u16 hl = bf16_hi(h - bf16f(hh));
            const u32 newtag = (u32)(((t + 1) >> 1) & 1);
            const u32 wd = (u32)hh | ((((u32)hl & 0xFFFEu) | newtag) << 16);
            u32* dst = hx + (((size_t)((t + 1) & 1) * 2 + d) * 64 + c * 16 + bi) * 256 + s * 16 + u;
            __hip_atomic_store(dst, wd, __ATOMIC_RELAXED, __HIP_MEMORY_SCOPE_AGENT);
            if (POOL && t < lens_sh[bi]) mx = fmaxf(mx, h);
            if (WRITE_H) ho_hi[bi * 16 + u] = hh;
        }

        if (WRITE_H) {
            __syncthreads();   // ho_hi ready
            if (tid < 32) {
                const int bi = tid >> 1, part = tid & 1;
                const int len_b = lens_sh[bi];
                const int pos = (d == 0) ? t : ((t < len_b) ? (len_b - 1 - t) : t);
                *(int4v*)(H0 + ((size_t)(c * 16 + bi) * TT + pos) * 512 + d * 256 + s * 16 + part * 8)
                    = *(const int4v*)(ho_hi + bi * 16 + part * 8);
            }
        }
    }

    if (POOL) {
        const int u = tid >> 4, bi = tid & 15;
        outp[(size_t)(c * 16 + bi) * 512 + d * 256 + s * 16 + u] = mx;
    }
}

// ---------------- host launch ----------------
extern "C" void kernel_launch(void* const* d_in, const int* in_sizes, int n_in,
                              void* d_out, int out_size, void* d_ws, size_t ws_size,
                              hipStream_t stream)
{
    (void)in_sizes; (void)n_in; (void)out_size; (void)ws_size;
    const int*   x     = (const int*)d_in[0];
    const int*   slen  = (const int*)d_in[1];
    const float* embed = (const float*)d_in[2];
    const float* W[16];
    for (int i = 0; i < 16; i++) W[i] = (const float*)d_in[3 + i];
    float* out = (float*)d_out;

    char* p = (char*)d_ws;                                   // total ~63.5 MB
    u16* A0      = (u16*)p;   p += (size_t)MROWS * DIM * 2;  // 16.8 MB
    u16* H0      = (u16*)p;   p += (size_t)MROWS * 512 * 2;  // 33.6 MB
    u16* WihQ0hi = (u16*)p;   p += 524288 * 2;
    u16* WihQ0lo = (u16*)p;   p += 524288 * 2;
    u16* WhhQ0hi = (u16*)p;   p += 524288 * 2;
    u16* WhhQ0lo = (u16*)p;   p += 524288 * 2;
    u16* WihQ1hi = (u16*)p;   p += 1048576 * 2;
    u16* WihQ1lo = (u16*)p;   p += 1048576 * 2;
    u16* WhhQ1hi = (u16*)p;   p += 524288 * 2;
    u16* WhhQ1lo = (u16*)p;   p += 524288 * 2;
    float* bsum  = (float*)p; p += 4096 * 4;
    u32* hxp     = (u32*)p;   p += 131072 * 4;               // 512 KB: 2 layer-regions

    k_prep<<<10768, 256, 0, stream>>>(
        W[0], W[1], W[2], W[3], W[4], W[5], W[6], W[7],
        W[8], W[9], W[10], W[11], W[12], W[13], W[14], W[15],
        WihQ0hi, WihQ0lo, WhhQ0hi, WhhQ0lo, WihQ1hi, WihQ1lo, WhhQ1hi, WhhQ1lo,
        bsum, hxp);

    k_gather<<<8192, 256, 0, stream>>>(x, embed, A0);

    k_lstm<256, true, false><<<128, 256, 0, stream>>>(
        A0, WhhQ0hi, WhhQ0lo, WihQ0hi, WihQ0lo, bsum, slen,
        H0, nullptr, hxp);

    k_lstm<512, false, true><<<128, 256, 0, stream>>>(
        H0, WhhQ1hi, WhhQ1lo, WihQ1hi, WihQ1lo, bsum + 2048, slen,
        nullptr, out, hxp + 65536);
}

// Round 4
// 3282.172 us; speedup vs baseline: 2.8046x; 1.8743x over previous
//
#include <hip/hip_runtime.h>
#include <stdint.h>
#include <stddef.h>

// ---------------- problem constants ----------------
#define BATCH 64
#define TT    512
#define DIM   256
#define HID   256
#define MROWS (BATCH*TT)     // 32768

typedef unsigned short u16;
typedef unsigned int u32;
typedef __attribute__((ext_vector_type(8))) short  short8;   // 8 x bf16 bits (4 VGPRs) - MFMA A/B frag
typedef __attribute__((ext_vector_type(4))) float  f32x4;    // MFMA C/D frag
typedef __attribute__((ext_vector_type(4))) int    int4v;
typedef __attribute__((ext_vector_type(4))) unsigned short u16x4;

__device__ __forceinline__ u16 bf16_hi(float f) {
    union { float f; unsigned u; } v; v.f = f;
    unsigned r = v.u + 0x7fffu + ((v.u >> 16) & 1u);   // RNE
    return (u16)(r >> 16);
}
__device__ __forceinline__ float bf16f(u16 b) {
    union { unsigned u; float f; } v; v.u = ((unsigned)b) << 16;
    return v.f;
}
__device__ __forceinline__ float fsigmoid(float x) { return 1.f / (1.f + __expf(-x)); }
__device__ __forceinline__ float ftanh(float x) {
    x = fminf(15.f, fmaxf(-15.f, x));                  // avoid inf/inf
    float e = __expf(2.f * x);
    return (e - 1.f) / (e + 1.f);
}

// ---------------- prep: quantize weights to bf16 hi/lo, bias sums, zero tags ----------------
// elems: weights 2,621,440 | bsum 4096 | tags 256  => 2,625,792 -> 10257*256
__global__ __launch_bounds__(256) void k_prep(
    const float* __restrict__ Wih0f, const float* __restrict__ Whh0f, const float* __restrict__ bih0f, const float* __restrict__ bhh0f,
    const float* __restrict__ Wih0b, const float* __restrict__ Whh0b, const float* __restrict__ bih0b, const float* __restrict__ bhh0b,
    const float* __restrict__ Wih1f, const float* __restrict__ Whh1f, const float* __restrict__ bih1f, const float* __restrict__ bhh1f,
    const float* __restrict__ Wih1b, const float* __restrict__ Whh1b, const float* __restrict__ bih1b, const float* __restrict__ bhh1b,
    u16* __restrict__ WihQ0hi, u16* __restrict__ WihQ0lo,
    u16* __restrict__ WhhQ0hi, u16* __restrict__ WhhQ0lo,
    u16* __restrict__ WihQ1hi, u16* __restrict__ WihQ1lo,
    u16* __restrict__ WhhQ1hi, u16* __restrict__ WhhQ1lo,
    float* __restrict__ bsum, u32* __restrict__ tags)
{
    const int i = blockIdx.x * 256 + threadIdx.x;
    if (i < 2621440) {
        const float* src; u16* dhi; u16* dlo; int off;
        if      (i <  262144) { src = Wih0f; dhi = WihQ0hi;          dlo = WihQ0lo;          off = i; }
        else if (i <  524288) { src = Wih0b; dhi = WihQ0hi + 262144; dlo = WihQ0lo + 262144; off = i -  262144; }
        else if (i <  786432) { src = Whh0f; dhi = WhhQ0hi;          dlo = WhhQ0lo;          off = i -  524288; }
        else if (i < 1048576) { src = Whh0b; dhi = WhhQ0hi + 262144; dlo = WhhQ0lo + 262144; off = i -  786432; }
        else if (i < 1572864) { src = Wih1f; dhi = WihQ1hi;          dlo = WihQ1lo;          off = i - 1048576; }
        else if (i < 2097152) { src = Wih1b; dhi = WihQ1hi + 524288; dlo = WihQ1lo + 524288; off = i - 1572864; }
        else if (i < 2359296) { src = Whh1f; dhi = WhhQ1hi;          dlo = WhhQ1lo;          off = i - 2097152; }
        else                  { src = Whh1b; dhi = WhhQ1hi + 262144; dlo = WhhQ1lo + 262144; off = i - 2359296; }
        const float v = src[off];
        const u16 h = bf16_hi(v);
        dhi[off] = h;
        dlo[off] = bf16_hi(v - bf16f(h));
    } else if (i < 2621440 + 4096) {
        const int j = i - 2621440;
        const float* bihs[4] = { bih0f, bih0b, bih1f, bih1b };
        const float* bhhs[4] = { bhh0f, bhh0b, bhh1f, bhh1b };
        const int ld = j >> 10, k = j & 1023;
        bsum[j] = bihs[ld][k] + bhhs[ld][k];
    } else if (i < 2621440 + 4096 + 256) {
        tags[i - (2621440 + 4096)] = 0;   // monotonic step tags, re-zeroed every launch
    }
}

// ---------------- embedding gather -> A0 (bf16 hi only) ----------------
__global__ __launch_bounds__(256) void k_gather(
    const int* __restrict__ x, const float* __restrict__ embed, u16* __restrict__ A0)
{
    const int row = blockIdx.x * 4 + (threadIdx.x >> 6);
    const int col = (threadIdx.x & 63) * 4;
    const int xi = x[row];
    const f32x4 v = *(const f32x4*)(embed + (size_t)xi * DIM + col);
    u16x4 h;
    #pragma unroll
    for (int i = 0; i < 4; i++) h[i] = bf16_hi(v[i]);
    *(u16x4*)(A0 + (size_t)row * DIM + col) = h;
}

// ---------------- persistent bidirectional LSTM layer ----------------
// grid = 128 blocks: bid = s*8 + d*4 + c (s=16-unit slice, d=dir, c=batch-chunk of 16).
// Exchange protocol (per (d,c) group of 16 slice-blocks):
//   producer: pack h hi|lo u32 in LDS -> wave0: 64 coalesced 16B sc0sc1 stores
//             -> s_waitcnt vmcnt(0) -> ONE tag store (t+1).  (vmcnt completion of an
//             sc1 store = visible at coherence point => tag-after-data needs no fence)
//   consumer: all waves poll 16 contiguous tags (1 coalesced transaction/round);
//             then 4x coalesced 16B sc0sc1 loads/thread, gated by a pass-through
//             vmcnt(0) asm so no use can be hoisted above the wait.
// Data buffer parity-double-buffered (max inter-block skew = 1 step); tags monotonic.
template<int KIN, bool WRITE_H, bool POOL>
__global__ __launch_bounds__(256, 1) void k_lstm(
    const u16* __restrict__ Xin,                   // layer0: A0 [32768][256]; layer1: H0 [32768][512]
    const u16* __restrict__ WhhHi, const u16* __restrict__ WhhLo,   // [2][1024][256]
    const u16* __restrict__ WihHi, const u16* __restrict__ WihLo,   // [2][1024][KIN]
    const float* __restrict__ bsum,                // [2][1024] for this layer
    const int* __restrict__ slen,
    u16* __restrict__ H0,                          // layer0 out (hi) [32768][512] or null
    float* __restrict__ outp,                      // [64][512] pooled out or null
    u32* __restrict__ hx,                          // [2 parity][2 dir][64][256] packed hi|lo
    u32* __restrict__ tags)                        // [8 groups][16 slices] monotonic
{
    constexpr int KV = KIN / 32;        // MFMA k-blocks for input proj
    constexpr int CR = KIN / 8;         // 16B chunks per x row
    constexpr int NST = (16 * CR) / 256;

    const int bid = blockIdx.x;
    const int s = bid >> 3;
    const int d = (bid >> 2) & 1;
    const int c = bid & 3;
    const int tid = threadIdx.x;
    const int l = tid & 63, w = tid >> 6;

    __shared__ u16 xs[16 * KIN];        // swizzled x-tile (bf16 hi)
    __shared__ u16 hs_hi[16 * 256];
    __shared__ u16 hs_lo[16 * 256];
    __shared__ float g_lds[64 * 16];    // [gate*16+unit][batch]
    __shared__ u32 ho_pack[16 * 16];    // [batch][unit] packed hi|lo
    __shared__ int lens_sh[16];
    __shared__ int maxlen_sh;

    if (tid < 16) lens_sh[tid] = slen[c * 16 + tid];
    __syncthreads();
    if (tid == 0) {
        int m = 0;
        #pragma unroll
        for (int i = 0; i < 16; i++) m = max(m, lens_sh[i]);
        maxlen_sh = m;
    }
    __syncthreads();
    const int maxlen = maxlen_sh;

    // ---- persistent register-resident weight fragments (wave w = gate w) ----
    const int rbase = d * 1024 + w * 256 + s * 16;
    short8 wfh[8], wfl[8];
    #pragma unroll
    for (int kv = 0; kv < 8; kv++) {
        const size_t off = (size_t)(rbase + (l & 15)) * 256 + kv * 32 + ((l >> 4) << 3);
        wfh[kv] = *(const short8*)(WhhHi + off);
        wfl[kv] = *(const short8*)(WhhLo + off);
    }
    short8 uih[KV], uil[KV];
    #pragma unroll
    for (int kv = 0; kv < KV; kv++) {
        const size_t off = (size_t)(rbase + (l & 15)) * KIN + kv * 32 + ((l >> 4) << 3);
        uih[kv] = *(const short8*)(WihHi + off);
        uil[kv] = *(const short8*)(WihLo + off);
    }
    // pin weights: opaque identity stops the compiler re-loading them each step
    #pragma unroll
    for (int kv = 0; kv < 8; kv++) {
        asm volatile("" : "+v"(wfh[kv]), "+v"(wfl[kv]));
    }
    #pragma unroll
    for (int kv = 0; kv < KV; kv++) {
        asm volatile("" : "+v"(uih[kv]), "+v"(uil[kv]));
    }
    float bias_g[4];
    {
        const int u = tid >> 4;
        #pragma unroll
        for (int g = 0; g < 4; g++) bias_g[g] = bsum[d * 1024 + g * 256 + s * 16 + u];
    }

    u32* tagp = tags + (d * 4 + c) * 16;
    float creg = 0.f, mx = -1e30f;
    const int bi_m = l & 15;
    const int swz = bi_m & 7;
    const int klane = l >> 4;

    for (int t = 0; t < maxlen; ++t) {
        // ---- (1) stage x-tile (plain cached loads; coalesced per wave) ----
        #pragma unroll
        for (int p = 0; p < NST; p++) {
            const int idx = p * 256 + tid;
            const int bi = idx / CR;
            const int ch = idx % CR;
            const int len_b = lens_sh[bi];
            const int pos = (d == 0) ? t : ((t < len_b) ? (len_b - 1 - t) : t);
            const short8 v = *(const short8*)(Xin + ((size_t)(c * 16 + bi) * TT + pos) * KIN + ch * 8);
            *(short8*)(xs + bi * KIN + (ch ^ (bi & 7)) * 8) = v;
        }

        // ---- (2) acquire h(t) ----
        if (t == 0) {
            const short8 z = {0,0,0,0,0,0,0,0};
            for (int i = tid; i < 512; i += 256) {
                ((short8*)hs_hi)[i] = z;
                ((short8*)hs_lo)[i] = z;
            }
        } else {
            // poll 16 tags, coalesced, per-wave exit
            int rounds = 0;
            for (;;) {
                const u32 tv = __hip_atomic_load(tagp + (l & 15), __ATOMIC_RELAXED, __HIP_MEMORY_SCOPE_AGENT);
                if (__all((int)(tv >= (u32)t))) break;
                if (++rounds > (1 << 17)) break;   // valve: degrade, never hang
                __builtin_amdgcn_s_sleep(2);
            }
            // one-shot data load: 4 interleaved quarters, each wave-inst = 1KB contiguous
            const u32* gbase = hx + (((size_t)(t & 1) * 2 + d) * 64 + c * 16) * 256;
            const u32* p0 = gbase + tid * 4;
            const u32* p1 = p0 + 1024;
            const u32* p2 = p0 + 2048;
            const u32* p3 = p0 + 3072;
            int4v w0, w1, w2, w3;
            asm volatile(
                "global_load_dwordx4 %0, %4, off sc0 sc1\n\t"
                "global_load_dwordx4 %1, %5, off sc0 sc1\n\t"
                "global_load_dwordx4 %2, %6, off sc0 sc1\n\t"
                "global_load_dwordx4 %3, %7, off sc0 sc1"
                : "=&v"(w0), "=&v"(w1), "=&v"(w2), "=&v"(w3)
                : "v"(p0), "v"(p1), "v"(p2), "v"(p3)
                : "memory");
            asm volatile("s_waitcnt vmcnt(0)"
                : "+v"(w0), "+v"(w1), "+v"(w2), "+v"(w3) :: "memory");
            // unpack -> swizzled LDS
            const int u0 = (tid & 63) * 4;          // 4 consecutive units
            const int ch = u0 >> 3;                  // chunk of 8 units
            const int co = u0 & 7;                   // 0 or 4 within chunk
            int4v wq[4] = {w0, w1, w2, w3};
            #pragma unroll
            for (int q = 0; q < 4; q++) {
                const int bi = q * 4 + (tid >> 6);
                u16x4 hi4, lo4;
                #pragma unroll
                for (int j = 0; j < 4; j++) {
                    const u32 wd = (u32)wq[q][j];
                    hi4[j] = (u16)(wd & 0xFFFFu);
                    lo4[j] = (u16)(wd >> 16);
                }
                *(u16x4*)(hs_hi + bi * 256 + (ch ^ (bi & 7)) * 8 + co) = hi4;
                *(u16x4*)(hs_lo + bi * 256 + (ch ^ (bi & 7)) * 8 + co) = lo4;
            }
        }
        __syncthreads();   // SYNC-B: xs & hs ready

        // ---- (3) gates = Whh.h (3-term) + Wih.x (2-term); 3 independent acc chains ----
        f32x4 acc_a = {0.f,0.f,0.f,0.f}, acc_b = {0.f,0.f,0.f,0.f}, acc_c = {0.f,0.f,0.f,0.f};
        #pragma unroll
        for (int kv = 0; kv < 8; kv++) {
            const int kc = kv * 4 + klane;
            const short8 bh = *(const short8*)(hs_hi + bi_m * 256 + (kc ^ swz) * 8);
            const short8 bl = *(const short8*)(hs_lo + bi_m * 256 + (kc ^ swz) * 8);
            acc_a = __builtin_amdgcn_mfma_f32_16x16x32_bf16(wfh[kv], bh, acc_a, 0, 0, 0);
            acc_b = __builtin_amdgcn_mfma_f32_16x16x32_bf16(wfl[kv], bh, acc_b, 0, 0, 0);
            acc_c = __builtin_amdgcn_mfma_f32_16x16x32_bf16(wfh[kv], bl, acc_c, 0, 0, 0);
        }
        #pragma unroll
        for (int kv = 0; kv < KV; kv++) {
            const int kc = kv * 4 + klane;
            const short8 bx = *(const short8*)(xs + bi_m * KIN + (kc ^ swz) * 8);
            acc_a = __builtin_amdgcn_mfma_f32_16x16x32_bf16(uih[kv], bx, acc_a, 0, 0, 0);
            acc_b = __builtin_amdgcn_mfma_f32_16x16x32_bf16(uil[kv], bx, acc_b, 0, 0, 0);
        }
        {
            const int r0 = w * 16 + klane * 4;
            #pragma unroll
            for (int r = 0; r < 4; r++)
                g_lds[(r0 + r) * 16 + bi_m] = (acc_a[r] + acc_b[r]) + acc_c[r];
        }
        __syncthreads();   // SYNC-C: gates ready

        // ---- (4) cell update: thread -> (unit u, batch bi); pack h into LDS ----
        {
            const int u = tid >> 4, bi = tid & 15;
            const float gi = g_lds[( 0 + u) * 16 + bi] + bias_g[0];
            const float gf = g_lds[(16 + u) * 16 + bi] + bias_g[1];
            const float gg = g_lds[(32 + u) * 16 + bi] + bias_g[2];
            const float go = g_lds[(48 + u) * 16 + bi] + bias_g[3];
            const float cc = fsigmoid(gf) * creg + fsigmoid(gi) * ftanh(gg);
            creg = cc;
            const float h = fsigmoid(go) * ftanh(cc);
            if (POOL && t < lens_sh[bi]) mx = fmaxf(mx, h);
            const u16 hh = bf16_hi(h);
            const u16 hl = bf16_hi(h - bf16f(hh));
            ho_pack[bi * 16 + u] = (u32)hh | ((u32)hl << 16);
        }
        __syncthreads();   // SYNC-D: ho_pack ready

        // ---- (5) publish: wave0 -> hx (16B coherent stores) + tag; wave1 -> H0 ----
        if (w == 0) {
            const int bi = l >> 2, q = l & 3;
            const int4v pv = *(const int4v*)(ho_pack + bi * 16 + q * 4);
            u32* dst = hx + (((size_t)((t + 1) & 1) * 2 + d) * 64 + c * 16 + bi) * 256 + s * 16 + q * 4;
            asm volatile("global_store_dwordx4 %0, %1, off sc0 sc1" :: "v"(dst), "v"(pv) : "memory");
            asm volatile("s_waitcnt vmcnt(0)" ::: "memory");   // data at coherence point
            if (l == 0)
                __hip_atomic_store(tagp + s, (u32)(t + 1), __ATOMIC_RELAXED, __HIP_MEMORY_SCOPE_AGENT);
        } else if (WRITE_H && w == 1) {
            const int bi = l >> 2, q = l & 3;
            const int4v pv = *(const int4v*)(ho_pack + bi * 16 + q * 4);
            u16x4 hv;
            #pragma unroll
            for (int j = 0; j < 4; j++) hv[j] = (u16)((u32)pv[j] & 0xFFFFu);
            const int len_b = lens_sh[bi];
            const int pos = (d == 0) ? t : ((t < len_b) ? (len_b - 1 - t) : t);
            *(u16x4*)(H0 + ((size_t)(c * 16 + bi) * TT + pos) * 512 + d * 256 + s * 16 + q * 4) = hv;
        }
        // no trailing barrier needed: next iteration's SYNC-B orders LDS reuse
    }

    if (POOL) {
        const int u = tid >> 4, bi = tid & 15;
        outp[(size_t)(c * 16 + bi) * 512 + d * 256 + s * 16 + u] = mx;
    }
}

// ---------------- host launch ----------------
extern "C" void kernel_launch(void* const* d_in, const int* in_sizes, int n_in,
                              void* d_out, int out_size, void* d_ws, size_t ws_size,
                              hipStream_t stream)
{
    (void)in_sizes; (void)n_in; (void)out_size; (void)ws_size;
    const int*   x     = (const int*)d_in[0];
    const int*   slen  = (const int*)d_in[1];
    const float* embed = (const float*)d_in[2];
    const float* W[16];
    for (int i = 0; i < 16; i++) W[i] = (const float*)d_in[3 + i];
    float* out = (float*)d_out;

    char* p = (char*)d_ws;                                   // total ~63.5 MB
    u16* A0      = (u16*)p;   p += (size_t)MROWS * DIM * 2;  // 16.8 MB
    u16* H0      = (u16*)p;   p += (size_t)MROWS * 512 * 2;  // 33.6 MB
    u16* WihQ0hi = (u16*)p;   p += 524288 * 2;
    u16* WihQ0lo = (u16*)p;   p += 524288 * 2;
    u16* WhhQ0hi = (u16*)p;   p += 524288 * 2;
    u16* WhhQ0lo = (u16*)p;   p += 524288 * 2;
    u16* WihQ1hi = (u16*)p;   p += 1048576 * 2;
    u16* WihQ1lo = (u16*)p;   p += 1048576 * 2;
    u16* WhhQ1hi = (u16*)p;   p += 524288 * 2;
    u16* WhhQ1lo = (u16*)p;   p += 524288 * 2;
    float* bsum  = (float*)p; p += 4096 * 4;
    u32* hxp     = (u32*)p;   p += 131072 * 4;               // data: 2 layer-regions
    u32* tagp    = (u32*)p;   p += 256 * 4;                  // tags: 2 x [8][16]

    k_prep<<<10257, 256, 0, stream>>>(
        W[0], W[1], W[2], W[3], W[4], W[5], W[6], W[7],
        W[8], W[9], W[10], W[11], W[12], W[13], W[14], W[15],
        WihQ0hi, WihQ0lo, WhhQ0hi, WhhQ0lo, WihQ1hi, WihQ1lo, WhhQ1hi, WhhQ1lo,
        bsum, tagp);

    k_gather<<<8192, 256, 0, stream>>>(x, embed, A0);

    k_lstm<256, true, false><<<128, 256, 0, stream>>>(
        A0, WhhQ0hi, WhhQ0lo, WihQ0hi, WihQ0lo, bsum, slen,
        H0, nullptr, hxp, tagp);

    k_lstm<512, false, true><<<128, 256, 0, stream>>>(
        H0, WhhQ1hi, WhhQ1lo, WihQ1hi, WihQ1lo, bsum + 2048, slen,
        nullptr, out, hxp + 65536, tagp + 128);
}

// Round 5
// 2603.358 us; speedup vs baseline: 3.5358x; 1.2607x over previous
//
#include <hip/hip_runtime.h>
#include <stdint.h>
#include <stddef.h>

// ---------------- problem constants ----------------
#define BATCH 64
#define TT    512
#define DIM   256
#define HID   256
#define MROWS (BATCH*TT)     // 32768

typedef unsigned short u16;
typedef unsigned int u32;
typedef __attribute__((ext_vector_type(8))) short  short8;   // 8 x bf16 bits (4 VGPRs) - MFMA A/B frag
typedef __attribute__((ext_vector_type(4))) float  f32x4;    // MFMA C/D frag
typedef __attribute__((ext_vector_type(4))) int    int4v;
typedef __attribute__((ext_vector_type(4))) unsigned short u16x4;

__device__ __forceinline__ u16 bf16_hi(float f) {
    union { float f; unsigned u; } v; v.f = f;
    unsigned r = v.u + 0x7fffu + ((v.u >> 16) & 1u);   // RNE
    return (u16)(r >> 16);
}
__device__ __forceinline__ float bf16f(u16 b) {
    union { unsigned u; float f; } v; v.u = ((unsigned)b) << 16;
    return v.f;
}
__device__ __forceinline__ float fsigmoid(float x) { return 1.f / (1.f + __expf(-x)); }
__device__ __forceinline__ float ftanh(float x) {
    x = fminf(15.f, fmaxf(-15.f, x));                  // avoid inf/inf
    float e = __expf(2.f * x);
    return (e - 1.f) / (e + 1.f);
}

// ---------------- prep: quantize weights to bf16 hi/lo, bias sums, init hx parity tags ----------------
// elems: weights 2,621,440 | bsum 4096 | hx 131072 => 2,756,608 -> 10768*256
__global__ __launch_bounds__(256) void k_prep(
    const float* __restrict__ Wih0f, const float* __restrict__ Whh0f, const float* __restrict__ bih0f, const float* __restrict__ bhh0f,
    const float* __restrict__ Wih0b, const float* __restrict__ Whh0b, const float* __restrict__ bih0b, const float* __restrict__ bhh0b,
    const float* __restrict__ Wih1f, const float* __restrict__ Whh1f, const float* __restrict__ bih1f, const float* __restrict__ bhh1f,
    const float* __restrict__ Wih1b, const float* __restrict__ Whh1b, const float* __restrict__ bih1b, const float* __restrict__ bhh1b,
    u16* __restrict__ WihQ0hi, u16* __restrict__ WihQ0lo,
    u16* __restrict__ WhhQ0hi, u16* __restrict__ WhhQ0lo,
    u16* __restrict__ WihQ1hi, u16* __restrict__ WihQ1lo,
    u16* __restrict__ WhhQ1hi, u16* __restrict__ WhhQ1lo,
    float* __restrict__ bsum, u32* __restrict__ hxp)
{
    const int i = blockIdx.x * 256 + threadIdx.x;
    if (i < 2621440) {
        const float* src; u16* dhi; u16* dlo; int off;
        if      (i <  262144) { src = Wih0f; dhi = WihQ0hi;          dlo = WihQ0lo;          off = i; }
        else if (i <  524288) { src = Wih0b; dhi = WihQ0hi + 262144; dlo = WihQ0lo + 262144; off = i -  262144; }
        else if (i <  786432) { src = Whh0f; dhi = WhhQ0hi;          dlo = WhhQ0lo;          off = i -  524288; }
        else if (i < 1048576) { src = Whh0b; dhi = WhhQ0hi + 262144; dlo = WhhQ0lo + 262144; off = i -  786432; }
        else if (i < 1572864) { src = Wih1f; dhi = WihQ1hi;          dlo = WihQ1lo;          off = i - 1048576; }
        else if (i < 2097152) { src = Wih1b; dhi = WihQ1hi + 524288; dlo = WihQ1lo + 524288; off = i - 1572864; }
        else if (i < 2359296) { src = Whh1f; dhi = WhhQ1hi;          dlo = WhhQ1lo;          off = i - 2097152; }
        else                  { src = Whh1b; dhi = WhhQ1hi + 262144; dlo = WhhQ1lo + 262144; off = i - 2359296; }
        const float v = src[off];
        const u16 h = bf16_hi(v);
        dhi[off] = h;
        dlo[off] = bf16_hi(v - bf16f(h));
    } else if (i < 2621440 + 4096) {
        const int j = i - 2621440;
        const float* bihs[4] = { bih0f, bih0b, bih1f, bih1b };
        const float* bhhs[4] = { bhh0f, bhh0b, bhh1f, bhh1b };
        const int ld = j >> 10, k = j & 1023;
        bsum[j] = bihs[ld][k] + bhhs[ld][k];
    } else if (i < 2621440 + 4096 + 131072) {
        // hx: 2 layer-regions x [2 parity][2 dir][64][256] u32, tag = bit16 (LSB of lo16).
        // First consumption of parity0 is T=2 (expect tag 1) -> init tag 0;
        // parity1 first consumed T=1 (expect tag 0) -> init tag 1.
        const int j = i - (2621440 + 4096);
        hxp[j] = ((j >> 15) & 1) ? 0x00010000u : 0u;
    }
}

// ---------------- embedding gather -> A0 (bf16 hi only) ----------------
__global__ __launch_bounds__(256) void k_gather(
    const int* __restrict__ x, const float* __restrict__ embed, u16* __restrict__ A0)
{
    const int row = blockIdx.x * 4 + (threadIdx.x >> 6);
    const int col = (threadIdx.x & 63) * 4;
    const int xi = x[row];
    const f32x4 v = *(const f32x4*)(embed + (size_t)xi * DIM + col);
    u16x4 h;
    #pragma unroll
    for (int i = 0; i < 4; i++) h[i] = bf16_hi(v[i]);
    *(u16x4*)(A0 + (size_t)row * DIM + col) = h;
}

// ---------------- persistent bidirectional LSTM layer ----------------
// grid = 128 blocks: bid = s*8 + d*4 + c (s=16-unit slice, d=dir, c=batch-chunk of 16).
// ONE-HOP exchange: h words are self-validating (tag bit16 = (T>>1)&1 for the h consumed
// at step T; parity double-buffer T&1). Producer: LDS pack -> wave0 64x16B sc0sc1 stores,
// NO wait, NO separate flag (a 16B store is a single transaction; its tag validates it).
// Consumer: retry loop of 4x16B sc0sc1 loads per thread; fold tag bits; per-wave __all.
// Race-free: validated data lives in registers; a parity slot is rewritten only 2 steps later.
template<int KIN, bool WRITE_H, bool POOL>
__global__ __launch_bounds__(256, 1) void k_lstm(
    const u16* __restrict__ Xin,                   // layer0: A0 [32768][256]; layer1: H0 [32768][512]
    const u16* __restrict__ WhhHi, const u16* __restrict__ WhhLo,   // [2][1024][256]
    const u16* __restrict__ WihHi, const u16* __restrict__ WihLo,   // [2][1024][KIN]
    const float* __restrict__ bsum,                // [2][1024] for this layer
    const int* __restrict__ slen,
    u16* __restrict__ H0,                          // layer0 out (hi) [32768][512] or null
    float* __restrict__ outp,                      // [64][512] pooled out or null
    u32* __restrict__ hx)                          // [2 parity][2 dir][64][256] packed hi|lo(+tag)
{
    constexpr int KV = KIN / 32;        // MFMA k-blocks for input proj
    constexpr int CR = KIN / 8;         // 16B chunks per x row
    constexpr int NST = (16 * CR) / 256;

    const int bid = blockIdx.x;
    const int s = bid >> 3;
    const int d = (bid >> 2) & 1;
    const int c = bid & 3;
    const int tid = threadIdx.x;
    const int l = tid & 63, w = tid >> 6;

    __shared__ u16 xs[16 * KIN];        // swizzled x-tile (bf16 hi)
    __shared__ u16 hs_hi[16 * 256];
    __shared__ u16 hs_lo[16 * 256];
    __shared__ float g_lds[64 * 16];    // [gate*16+unit][batch]
    __shared__ u32 ho_pack[16 * 16];    // [batch][unit] packed hi|lo(+tag)
    __shared__ int lens_sh[16];
    __shared__ int maxlen_sh;

    if (tid < 16) lens_sh[tid] = slen[c * 16 + tid];
    __syncthreads();
    if (tid == 0) {
        int m = 0;
        #pragma unroll
        for (int i = 0; i < 16; i++) m = max(m, lens_sh[i]);
        maxlen_sh = m;
    }
    __syncthreads();
    const int maxlen = maxlen_sh;

    // ---- persistent register-resident weight fragments (wave w = gate w) ----
    const int rbase = d * 1024 + w * 256 + s * 16;
    short8 wfh[8], wfl[8];
    #pragma unroll
    for (int kv = 0; kv < 8; kv++) {
        const size_t off = (size_t)(rbase + (l & 15)) * 256 + kv * 32 + ((l >> 4) << 3);
        wfh[kv] = *(const short8*)(WhhHi + off);
        wfl[kv] = *(const short8*)(WhhLo + off);
    }
    short8 uih[KV], uil[KV];
    #pragma unroll
    for (int kv = 0; kv < KV; kv++) {
        const size_t off = (size_t)(rbase + (l & 15)) * KIN + kv * 32 + ((l >> 4) << 3);
        uih[kv] = *(const short8*)(WihHi + off);
        uil[kv] = *(const short8*)(WihLo + off);
    }
    // pin weights: opaque identity stops the compiler re-loading them each step
    #pragma unroll
    for (int kv = 0; kv < 8; kv++) {
        asm volatile("" : "+v"(wfh[kv]), "+v"(wfl[kv]));
    }
    #pragma unroll
    for (int kv = 0; kv < KV; kv++) {
        asm volatile("" : "+v"(uih[kv]), "+v"(uil[kv]));
    }
    float bias_g[4];
    {
        const int u = tid >> 4;
        #pragma unroll
        for (int g = 0; g < 4; g++) bias_g[g] = bsum[d * 1024 + g * 256 + s * 16 + u];
    }

    float creg = 0.f, mx = -1e30f;
    const int bi_m = l & 15;
    const int swz = bi_m & 7;
    const int klane = l >> 4;

    for (int t = 0; t < maxlen; ++t) {
        // ---- (1) stage x-tile (plain cached loads; coalesced per wave; overlaps exchange wait) ----
        #pragma unroll
        for (int p = 0; p < NST; p++) {
            const int idx = p * 256 + tid;
            const int bi = idx / CR;
            const int ch = idx % CR;
            const int len_b = lens_sh[bi];
            const int pos = (d == 0) ? t : ((t < len_b) ? (len_b - 1 - t) : t);
            const short8 v = *(const short8*)(Xin + ((size_t)(c * 16 + bi) * TT + pos) * KIN + ch * 8);
            *(short8*)(xs + bi * KIN + (ch ^ (bi & 7)) * 8) = v;
        }

        // ---- (2) acquire h(t): self-validating retry load (ONE coherent hop) ----
        if (t == 0) {
            const short8 z = {0,0,0,0,0,0,0,0};
            for (int i = tid; i < 512; i += 256) {
                ((short8*)hs_hi)[i] = z;
                ((short8*)hs_lo)[i] = z;
            }
        } else {
            const u32* gbase = hx + (((size_t)(t & 1) * 2 + d) * 64 + c * 16) * 256;
            const u32* p0 = gbase + tid * 4;
            const u32* p1 = p0 + 1024;
            const u32* p2 = p0 + 2048;
            const u32* p3 = p0 + 3072;
            const int expect = (t >> 1) & 1;
            int4v w0, w1, w2, w3;
            int rounds = 0;
            for (;;) {
                asm volatile(
                    "global_load_dwordx4 %0, %4, off sc0 sc1\n\t"
                    "global_load_dwordx4 %1, %5, off sc0 sc1\n\t"
                    "global_load_dwordx4 %2, %6, off sc0 sc1\n\t"
                    "global_load_dwordx4 %3, %7, off sc0 sc1"
                    : "=&v"(w0), "=&v"(w1), "=&v"(w2), "=&v"(w3)
                    : "v"(p0), "v"(p1), "v"(p2), "v"(p3)
                    : "memory");
                asm volatile("s_waitcnt vmcnt(0)"
                    : "+v"(w0), "+v"(w1), "+v"(w2), "+v"(w3) :: "memory");
                u32 aw = 0xFFFFFFFFu, ow = 0u;
                #pragma unroll
                for (int j = 0; j < 4; j++) {
                    aw &= (u32)w0[j]; ow |= (u32)w0[j];
                    aw &= (u32)w1[j]; ow |= (u32)w1[j];
                    aw &= (u32)w2[j]; ow |= (u32)w2[j];
                    aw &= (u32)w3[j]; ow |= (u32)w3[j];
                }
                const int ok = expect ? (int)((aw >> 16) & 1u)
                                      : (int)(((ow >> 16) & 1u) ^ 1u);
                if (__all(ok)) break;
                if (++rounds > (1 << 17)) break;   // valve: degrade, never hang
                __builtin_amdgcn_s_sleep(1);
            }
            // unpack -> swizzled LDS
            const int u0 = (tid & 63) * 4;          // 4 consecutive units
            const int ch = u0 >> 3;                  // chunk of 8 units
            const int co = u0 & 7;                   // 0 or 4 within chunk
            int4v wq[4] = {w0, w1, w2, w3};
            #pragma unroll
            for (int q = 0; q < 4; q++) {
                const int bi = q * 4 + (tid >> 6);
                u16x4 hi4, lo4;
                #pragma unroll
                for (int j = 0; j < 4; j++) {
                    const u32 wd = (u32)wq[q][j];
                    hi4[j] = (u16)(wd & 0xFFFFu);
                    lo4[j] = (u16)(wd >> 16);
                }
                *(u16x4*)(hs_hi + bi * 256 + (ch ^ (bi & 7)) * 8 + co) = hi4;
                *(u16x4*)(hs_lo + bi * 256 + (ch ^ (bi & 7)) * 8 + co) = lo4;
            }
        }
        __syncthreads();   // SYNC-B: xs & hs ready

        // ---- (3) gates = Whh.h (3-term) + Wih.x (2-term); 3 independent acc chains ----
        f32x4 acc_a = {0.f,0.f,0.f,0.f}, acc_b = {0.f,0.f,0.f,0.f}, acc_c = {0.f,0.f,0.f,0.f};
        #pragma unroll
        for (int kv = 0; kv < 8; kv++) {
            const int kc = kv * 4 + klane;
            const short8 bh = *(const short8*)(hs_hi + bi_m * 256 + (kc ^ swz) * 8);
            const short8 bl = *(const short8*)(hs_lo + bi_m * 256 + (kc ^ swz) * 8);
            acc_a = __builtin_amdgcn_mfma_f32_16x16x32_bf16(wfh[kv], bh, acc_a, 0, 0, 0);
            acc_b = __builtin_amdgcn_mfma_f32_16x16x32_bf16(wfl[kv], bh, acc_b, 0, 0, 0);
            acc_c = __builtin_amdgcn_mfma_f32_16x16x32_bf16(wfh[kv], bl, acc_c, 0, 0, 0);
        }
        #pragma unroll
        for (int kv = 0; kv < KV; kv++) {
            const int kc = kv * 4 + klane;
            const short8 bx = *(const short8*)(xs + bi_m * KIN + (kc ^ swz) * 8);
            acc_a = __builtin_amdgcn_mfma_f32_16x16x32_bf16(uih[kv], bx, acc_a, 0, 0, 0);
            acc_b = __builtin_amdgcn_mfma_f32_16x16x32_bf16(uil[kv], bx, acc_b, 0, 0, 0);
        }
        {
            const int r0 = w * 16 + klane * 4;
            #pragma unroll
            for (int r = 0; r < 4; r++)
                g_lds[(r0 + r) * 16 + bi_m] = (acc_a[r] + acc_b[r]) + acc_c[r];
        }
        __syncthreads();   // SYNC-C: gates ready

        // ---- (4) cell update: thread -> (unit u, batch bi); pack h (tag embedded) ----
        {
            const int u = tid >> 4, bi = tid & 15;
            const float gi = g_lds[( 0 + u) * 16 + bi] + bias_g[0];
            const float gf = g_lds[(16 + u) * 16 + bi] + bias_g[1];
            const float gg = g_lds[(32 + u) * 16 + bi] + bias_g[2];
            const float go = g_lds[(48 + u) * 16 + bi] + bias_g[3];
            const float cc = fsigmoid(gf) * creg + fsigmoid(gi) * ftanh(gg);
            creg = cc;
            const float h = fsigmoid(go) * ftanh(cc);
            if (POOL && t < lens_sh[bi]) mx = fmaxf(mx, h);
            const u16 hh = bf16_hi(h);
            const u32 hl = ((u32)bf16_hi(h - bf16f(hh)) & 0xFFFEu) | (u32)(((t + 1) >> 1) & 1);
            ho_pack[bi * 16 + u] = (u32)hh | (hl << 16);
        }
        __syncthreads();   // SYNC-D: ho_pack ready

        // ---- (5) publish: wave0 -> hx (16B coherent stores, NO wait); wave1 -> H0 ----
        if (w == 0) {
            const int bi = l >> 2, q = l & 3;
            const int4v pv = *(const int4v*)(ho_pack + bi * 16 + q * 4);
            u32* dst = hx + (((size_t)((t + 1) & 1) * 2 + d) * 64 + c * 16 + bi) * 256 + s * 16 + q * 4;
            asm volatile("global_store_dwordx4 %0, %1, off sc0 sc1" :: "v"(dst), "v"(pv) : "memory");
        } else if (WRITE_H && w == 1) {
            const int bi = l >> 2, q = l & 3;
            const int4v pv = *(const int4v*)(ho_pack + bi * 16 + q * 4);
            u16x4 hv;
            #pragma unroll
            for (int j = 0; j < 4; j++) hv[j] = (u16)((u32)pv[j] & 0xFFFFu);
            const int len_b = lens_sh[bi];
            const int pos = (d == 0) ? t : ((t < len_b) ? (len_b - 1 - t) : t);
            *(u16x4*)(H0 + ((size_t)(c * 16 + bi) * TT + pos) * 512 + d * 256 + s * 16 + q * 4) = hv;
        }
        // no trailing barrier: next iteration's SYNC-B orders LDS reuse
    }

    if (POOL) {
        const int u = tid >> 4, bi = tid & 15;
        outp[(size_t)(c * 16 + bi) * 512 + d * 256 + s * 16 + u] = mx;
    }
}

// ---------------- host launch ----------------
extern "C" void kernel_launch(void* const* d_in, const int* in_sizes, int n_in,
                              void* d_out, int out_size, void* d_ws, size_t ws_size,
                              hipStream_t stream)
{
    (void)in_sizes; (void)n_in; (void)out_size; (void)ws_size;
    const int*   x     = (const int*)d_in[0];
    const int*   slen  = (const int*)d_in[1];
    const float* embed = (const float*)d_in[2];
    const float* W[16];
    for (int i = 0; i < 16; i++) W[i] = (const float*)d_in[3 + i];
    float* out = (float*)d_out;

    char* p = (char*)d_ws;                                   // total ~63.5 MB
    u16* A0      = (u16*)p;   p += (size_t)MROWS * DIM * 2;  // 16.8 MB
    u16* H0      = (u16*)p;   p += (size_t)MROWS * 512 * 2;  // 33.6 MB
    u16* WihQ0hi = (u16*)p;   p += 524288 * 2;
    u16* WihQ0lo = (u16*)p;   p += 524288 * 2;
    u16* WhhQ0hi = (u16*)p;   p += 524288 * 2;
    u16* WhhQ0lo = (u16*)p;   p += 524288 * 2;
    u16* WihQ1hi = (u16*)p;   p += 1048576 * 2;
    u16* WihQ1lo = (u16*)p;   p += 1048576 * 2;
    u16* WhhQ1hi = (u16*)p;   p += 524288 * 2;
    u16* WhhQ1lo = (u16*)p;   p += 524288 * 2;
    float* bsum  = (float*)p; p += 4096 * 4;
    u32* hxp     = (u32*)p;   p += 131072 * 4;               // 2 layer-regions, parity-tagged

    k_prep<<<10768, 256, 0, stream>>>(
        W[0], W[1], W[2], W[3], W[4], W[5], W[6], W[7],
        W[8], W[9], W[10], W[11], W[12], W[13], W[14], W[15],
        WihQ0hi, WihQ0lo, WhhQ0hi, WhhQ0lo, WihQ1hi, WihQ1lo, WhhQ1hi, WhhQ1lo,
        bsum, hxp);

    k_gather<<<8192, 256, 0, stream>>>(x, embed, A0);

    k_lstm<256, true, false><<<128, 256, 0, stream>>>(
        A0, WhhQ0hi, WhhQ0lo, WihQ0hi, WihQ0lo, bsum, slen,
        H0, nullptr, hxp);

    k_lstm<512, false, true><<<128, 256, 0, stream>>>(
        H0, WhhQ1hi, WhhQ1lo, WihQ1hi, WihQ1lo, bsum + 2048, slen,
        nullptr, out, hxp + 65536);
}